// Round 7
// baseline (684.737 us; speedup 1.0000x reference)
//
#include <hip/hip_runtime.h>
#include <hip/hip_bf16.h>

// Block_45810121179249: 2x (single-head attn + residual + LayerNorm)
// B=4, S=4096, E=256. FP32 in/out; internal bf16 MFMA pipeline.
//
// Round 7: round-6 structure (V streamed from global VT with rolling prefetch,
// single __syncthreads per K tile, K LDS-double-buffered) with the P-buffer
// race fixed: Pb is now 32 rows per wave (both strips), strip t writes rows
// t*16..t*16+15 and ap[t] reads the same rows.

typedef __attribute__((ext_vector_type(8))) short bf16x8;  // 8 bf16 = 4 VGPRs
typedef __attribute__((ext_vector_type(4))) float f32x4;

#define MFMA_16x16x32(A, B, C) __builtin_amdgcn_mfma_f32_16x16x32_bf16(A, B, C, 0, 0, 0)

#define CP16(g, l)                                                              \
    __builtin_amdgcn_global_load_lds(                                           \
        (const __attribute__((address_space(1))) void*)(g),                     \
        (__attribute__((address_space(3))) void*)(l), 16, 0, 0)

static __device__ __forceinline__ short f2bf(float f) {
    __hip_bfloat16 h = __float2bfloat16(f);
    return __builtin_bit_cast(short, h);
}
static __device__ __forceinline__ float bf2f(short s) {
    unsigned int u = ((unsigned int)(unsigned short)s) << 16;
    return __builtin_bit_cast(float, u);
}
static __device__ __forceinline__ float ld1(const float* p) { return *p; }
static __device__ __forceinline__ float ld1(const short* p) { return bf2f(*p); }
static __device__ __forceinline__ void st1(float* p, float v) { *p = v; }
static __device__ __forceinline__ void st1(short* p, float v) { *p = f2bf(v); }

static __device__ __forceinline__ bf16x8 ldA8(const short* p) {
    return *reinterpret_cast<const bf16x8*>(p);
}
static __device__ __forceinline__ bf16x8 ldA8(const float* p) {
    float4 f0 = *reinterpret_cast<const float4*>(p);
    float4 f1 = *reinterpret_cast<const float4*>(p + 4);
    bf16x8 r;
    r[0] = f2bf(f0.x); r[1] = f2bf(f0.y); r[2] = f2bf(f0.z); r[3] = f2bf(f0.w);
    r[4] = f2bf(f1.x); r[5] = f2bf(f1.y); r[6] = f2bf(f1.z); r[7] = f2bf(f1.w);
    return r;
}

// ---- staging helpers (256-thread version, proj kernel) ---------------------
template <int NCH256>
static __device__ __forceinline__ void stage_rows(const short* __restrict__ g,
                                                  short* s, int tid) {
    const int wave = tid >> 6;
#pragma unroll
    for (int j = 0; j < NCH256; ++j) {
        const int idx = j * 256 + tid;
        const int row = idx >> 5, c = idx & 31;
        CP16(g + row * 256 + ((c ^ (row & 7)) << 3),
             s + ((j * 256 + wave * 64) << 3));
    }
}
// ---- K staging (512-thread): 64 rows x 256 e, chunk XOR-swizzled by row&7 --
static __device__ __forceinline__ void stage_k512(const short* __restrict__ g,
                                                  short* s, int tid) {
    const int wave = tid >> 6;
#pragma unroll
    for (int j = 0; j < 4; ++j) {
        const int idx = j * 512 + tid;
        const int row = idx >> 5, c = idx & 31;
        CP16(g + row * 256 + ((c ^ (row & 7)) << 3),
             s + ((j * 512 + wave * 64) << 3));
    }
}

// ---------------- fp32 -> bf16 weight conversion (6 x 65536) ----------------
__global__ __launch_bounds__(256) void cvt_w_kernel(
    const float* __restrict__ w0, const float* __restrict__ w1,
    const float* __restrict__ w2, const float* __restrict__ w3,
    const float* __restrict__ w4, const float* __restrict__ w5,
    short* __restrict__ wb)
{
    const int idx = (blockIdx.x * 256 + threadIdx.x) * 8;   // grid 192 -> exact
    const int w = idx >> 16, off = idx & 65535;
    const float* src = w0;
    if (w == 1) src = w1;
    else if (w == 2) src = w2;
    else if (w == 3) src = w3;
    else if (w == 4) src = w4;
    else if (w == 5) src = w5;
    *reinterpret_cast<bf16x8*>(wb + w * 65536 + off) = ldA8(src + off);
}

// ---------------- QKV projection, W staged in LDS ----------------
template <typename TX>
__global__ __launch_bounds__(256, 2) void qkv_proj_kernel(
    const TX* __restrict__ X,
    const short* __restrict__ Wq, const float* __restrict__ bq,
    const short* __restrict__ Wk, const float* __restrict__ bk,
    const short* __restrict__ Wv, const float* __restrict__ bv,
    short* __restrict__ Qo, short* __restrict__ Ko, short* __restrict__ VTo)
{
    __shared__ __attribute__((aligned(16))) short Wt[128 * 256];  // 64 KB half
    const int tid  = threadIdx.x;
    const int lane = tid & 63;
    const int wave = tid >> 6;
    const int c16  = lane & 15;
    const int quad = lane >> 4;
    const int which = blockIdx.y;
    const int m0 = blockIdx.x * 64 + wave * 16;

    const short* W    = (which == 0) ? Wq : (which == 1) ? Wk : Wv;
    const float* bias = (which == 0) ? bq : (which == 1) ? bk : bv;

    bf16x8 a[8];
#pragma unroll
    for (int ke = 0; ke < 8; ++ke)
        a[ke] = ldA8(X + (m0 + c16) * 256 + ke * 32 + quad * 8);

    f32x4 acc[16];
#pragma unroll
    for (int nb = 0; nb < 16; ++nb) { f32x4 z = {0.f, 0.f, 0.f, 0.f}; acc[nb] = z; }

#pragma unroll
    for (int half = 0; half < 2; ++half) {
        if (half) __syncthreads();
        stage_rows<16>(W + half * 128 * 256, Wt, tid);
        __syncthreads();
#pragma unroll
        for (int nb8 = 0; nb8 < 8; ++nb8) {
            const int nb = half * 8 + nb8;
            const short* wr = Wt + (nb8 * 16 + c16) * 256;
#pragma unroll
            for (int ke = 0; ke < 8; ++ke) {
                bf16x8 b = *reinterpret_cast<const bf16x8*>(
                    wr + (((ke * 4 + quad) ^ (c16 & 7)) << 3));
                acc[nb] = MFMA_16x16x32(a[ke], b, acc[nb]);
            }
        }
    }

    if (which < 2) {
        short* dst = (which == 0) ? Qo : Ko;
#pragma unroll
        for (int nb = 0; nb < 16; ++nb) {
            const int o = nb * 16 + c16;
            const float bb_ = bias[o];
#pragma unroll
            for (int r = 0; r < 4; ++r)
                dst[(m0 + quad * 4 + r) * 256 + o] = f2bf(acc[nb][r] + bb_);
        }
    } else {
#pragma unroll
        for (int nb = 0; nb < 16; ++nb) {
            const int o = nb * 16 + c16;
            const float bb_ = bias[o];
            const int row = m0 + quad * 4;
            const int batch = row >> 12;
            const int n = row & 4095;
            ushort4 pk;
            pk.x = (unsigned short)f2bf(acc[nb][0] + bb_);
            pk.y = (unsigned short)f2bf(acc[nb][1] + bb_);
            pk.z = (unsigned short)f2bf(acc[nb][2] + bb_);
            pk.w = (unsigned short)f2bf(acc[nb][3] + bb_);
            *reinterpret_cast<ushort4*>(VTo + (size_t)batch * (256 * 4096) + o * 4096 + n) = pk;
        }
    }
}

// ---------------- split-K flash attention partial ---------------------------
// combo = ((bi&7)<<1)|(bi>>7): each XCD sees 2 (batch,ks) pairs -> L2-local.
// Per tile kt: syncthreads (K(kt) staged) -> stage K(kt+1) -> QK(kt) ->
// softmax/Pwrite(kt) -> PV(kt-1) with V streamed from global (prefetched) ->
// ap-load(kt). Single barrier per tile; V never touches LDS.
__global__ __launch_bounds__(512, 2) void attn_part_kernel(
    const short* __restrict__ Qb, const short* __restrict__ Kb,
    const short* __restrict__ VTb,
    short* __restrict__ Op, float* __restrict__ Lo)
{
    __shared__ __attribute__((aligned(16))) short Kt[2][64 * 256];   // 2x32 KB
    __shared__ __attribute__((aligned(16))) short Pb[8][32 * 72];    // 36 KB

    const int tid  = threadIdx.x;
    const int lane = tid & 63;
    const int wave = tid >> 6;
    const int c16  = lane & 15;
    const int quad = lane >> 4;
    const int bi = blockIdx.x;
    const int combo = ((bi & 7) << 1) | ((bi >> 7) & 1);
    const int batch = combo >> 2;
    const int ks    = combo & 3;
    const int qt    = (bi >> 3) & 15;
    const size_t bb = (size_t)batch * (4096 * 256);
    const int rw = qt * 256 + wave * 32;          // wave's first q row
    const int kbase = ks * 1024;

    bf16x8 qf[2][8];
#pragma unroll
    for (int t = 0; t < 2; ++t)
#pragma unroll
        for (int ke = 0; ke < 8; ++ke)
            qf[t][ke] = *reinterpret_cast<const bf16x8*>(
                Qb + bb + (rw + t * 16 + c16) * 256 + ke * 32 + quad * 8);

    f32x4 oa[2][16];
#pragma unroll
    for (int t = 0; t < 2; ++t)
#pragma unroll
        for (int nb = 0; nb < 16; ++nb) { f32x4 z = {0.f, 0.f, 0.f, 0.f}; oa[t][nb] = z; }
    float lsum[2][4];
#pragma unroll
    for (int t = 0; t < 2; ++t)
#pragma unroll
        for (int r = 0; r < 4; ++r) lsum[t][r] = 0.f;

    constexpr float K1 = 1.4426950408889634f / 64.0f;  // log2(e)/sqrt(4096)
    short* pw = &Pb[wave][0];
    bf16x8 ap[2][2];   // P A-fragments, carried to next iteration's PV
    // per-lane V base: row e = c16 (+16*nb), key offset quad*8 (+32 for v1)
    const short* vbase = VTb + bb + (size_t)c16 * 4096 + quad * 8;

    stage_k512(Kb + bb + kbase * 256, &Kt[0][0], tid);

    for (int kt = 0; kt < 16; ++kt) {
        __syncthreads();   // K(kt) staged; K slot (kt+1)&1 free
        if (kt + 1 < 16)
            stage_k512(Kb + bb + (kbase + (kt + 1) * 64) * 256, &Kt[(kt + 1) & 1][0], tid);
        const short* K = &Kt[kt & 1][0];

        // ---- S = Q K^T (both strips share each K fragment) ----
        f32x4 s[2][4];
#pragma unroll
        for (int t = 0; t < 2; ++t)
#pragma unroll
            for (int nb = 0; nb < 4; ++nb) { f32x4 z = {0.f, 0.f, 0.f, 0.f}; s[t][nb] = z; }
#pragma unroll
        for (int nb = 0; nb < 4; ++nb) {
            const short* kr = K + (nb * 16 + c16) * 256;
#pragma unroll
            for (int ke = 0; ke < 8; ++ke) {
                bf16x8 kf = *reinterpret_cast<const bf16x8*>(
                    kr + (((ke * 4 + quad) ^ (c16 & 7)) << 3));
                s[0][nb] = MFMA_16x16x32(qf[0][ke], kf, s[0][nb]);
                s[1][nb] = MFMA_16x16x32(qf[1][ke], kf, s[1][nb]);
            }
        }

        // ---- first V pair of tile kt-1: issue before softmax (hide latency)
        const short* vt = vbase + kbase + (kt - 1) * 64;
        bf16x8 v0, v1;
        if (kt > 0) {
            v0 = *reinterpret_cast<const bf16x8*>(vt);
            v1 = *reinterpret_cast<const bf16x8*>(vt + 32);
        }

        // ---- p = exp2(z*K1); per-lane l; P(strip t) -> rows t*16.. ----
#pragma unroll
        for (int t = 0; t < 2; ++t) {
#pragma unroll
            for (int nb = 0; nb < 4; ++nb) {
#pragma unroll
                for (int r = 0; r < 4; ++r) {
                    const float pv = exp2f(s[t][nb][r] * K1);
                    lsum[t][r] += pv;
                    pw[(t * 16 + quad * 4 + r) * 72 + nb * 16 + c16] = f2bf(pv);
                }
            }
        }

        // ---- PV of tile kt-1: V streamed from global, rolling prefetch ----
        if (kt > 0) {
#pragma unroll
            for (int nb = 0; nb < 16; ++nb) {
                bf16x8 n0, n1;
                if (nb < 15) {
                    const short* vn = vt + (size_t)(nb + 1) * (16 * 4096);
                    n0 = *reinterpret_cast<const bf16x8*>(vn);
                    n1 = *reinterpret_cast<const bf16x8*>(vn + 32);
                }
                oa[0][nb] = MFMA_16x16x32(ap[0][0], v0, oa[0][nb]);
                oa[0][nb] = MFMA_16x16x32(ap[0][1], v1, oa[0][nb]);
                oa[1][nb] = MFMA_16x16x32(ap[1][0], v0, oa[1][nb]);
                oa[1][nb] = MFMA_16x16x32(ap[1][1], v1, oa[1][nb]);
                v0 = n0; v1 = n1;
            }
        }

        // ---- A-fragments of P(kt) for next iteration's PV ----
#pragma unroll
        for (int t = 0; t < 2; ++t) {
            ap[t][0] = *reinterpret_cast<const bf16x8*>(pw + (t * 16 + c16) * 72 + quad * 8);
            ap[t][1] = *reinterpret_cast<const bf16x8*>(pw + (t * 16 + c16) * 72 + 32 + quad * 8);
        }
    }

    // ---- final PV (tile 15) ----
    {
        const short* vt = vbase + kbase + 15 * 64;
        bf16x8 v0 = *reinterpret_cast<const bf16x8*>(vt);
        bf16x8 v1 = *reinterpret_cast<const bf16x8*>(vt + 32);
#pragma unroll
        for (int nb = 0; nb < 16; ++nb) {
            bf16x8 n0, n1;
            if (nb < 15) {
                const short* vn = vt + (size_t)(nb + 1) * (16 * 4096);
                n0 = *reinterpret_cast<const bf16x8*>(vn);
                n1 = *reinterpret_cast<const bf16x8*>(vn + 32);
            }
            oa[0][nb] = MFMA_16x16x32(ap[0][0], v0, oa[0][nb]);
            oa[0][nb] = MFMA_16x16x32(ap[0][1], v1, oa[0][nb]);
            oa[1][nb] = MFMA_16x16x32(ap[1][0], v0, oa[1][nb]);
            oa[1][nb] = MFMA_16x16x32(ap[1][1], v1, oa[1][nb]);
            v0 = n0; v1 = n1;
        }
    }

    // ---- reduce l across the 16 key-lanes; write bf16 partials ----
#pragma unroll
    for (int t = 0; t < 2; ++t) {
#pragma unroll
        for (int r = 0; r < 4; ++r) {
            float rs = lsum[t][r];
            rs += __shfl_xor(rs, 1, 64);
            rs += __shfl_xor(rs, 2, 64);
            rs += __shfl_xor(rs, 4, 64);
            rs += __shfl_xor(rs, 8, 64);
            const int grow = rw + t * 16 + quad * 4 + r;
            const size_t ridx = (size_t)ks * 16384 + batch * 4096 + grow;
#pragma unroll
            for (int nb = 0; nb < 16; ++nb)
                Op[ridx * 256 + nb * 16 + c16] = f2bf(oa[t][nb][r]);
            if (c16 == 0) Lo[ridx] = rs;
        }
    }
}

// ---------------- merge splits + residual + LayerNorm ----------------
template <typename TRES, typename TOUT>
__global__ __launch_bounds__(256) void merge_ln_kernel(
    const short* __restrict__ Op, const float* __restrict__ Lo,
    const TRES* __restrict__ res, const float* __restrict__ gamma,
    const float* __restrict__ beta, TOUT* __restrict__ out)
{
    const int lane = threadIdx.x & 63;
    const int wave = threadIdx.x >> 6;
    const int row = blockIdx.x * 4 + wave;          // batch*4096 + local row
    const float li = 1.0f / (Lo[row] + Lo[16384 + row] +
                             Lo[32768 + row] + Lo[49152 + row]);
    const int e = lane * 4;
    float o[4] = {0.f, 0.f, 0.f, 0.f};
#pragma unroll
    for (int s = 0; s < 4; ++s) {
        ushort4 u = *reinterpret_cast<const ushort4*>(
            Op + ((size_t)s * 16384 + row) * 256 + e);
        o[0] += bf2f((short)u.x);
        o[1] += bf2f((short)u.y);
        o[2] += bf2f((short)u.z);
        o[3] += bf2f((short)u.w);
    }
    float y[4];
#pragma unroll
    for (int i = 0; i < 4; ++i)
        y[i] = o[i] * li + ld1(res + (size_t)row * 256 + e + i);

    float sum = y[0] + y[1] + y[2] + y[3];
    float sq  = y[0]*y[0] + y[1]*y[1] + y[2]*y[2] + y[3]*y[3];
#pragma unroll
    for (int d = 1; d < 64; d <<= 1) {
        sum += __shfl_xor(sum, d, 64);
        sq  += __shfl_xor(sq,  d, 64);
    }
    const float mean = sum * (1.0f / 256.0f);
    const float var  = sq * (1.0f / 256.0f) - mean * mean;
    const float rstd = rsqrtf(var + 1e-5f);
#pragma unroll
    for (int i = 0; i < 4; ++i)
        st1(out + (size_t)row * 256 + e + i,
            (y[i] - mean) * rstd * gamma[e + i] + beta[e + i]);
}

extern "C" void kernel_launch(void* const* d_in, const int* in_sizes, int n_in,
                              void* d_out, int out_size, void* d_ws, size_t ws_size,
                              hipStream_t stream) {
    const float* x   = (const float*)d_in[0];
    const float* Wq1 = (const float*)d_in[1];
    const float* bq1 = (const float*)d_in[2];
    const float* Wk1 = (const float*)d_in[3];
    const float* bk1 = (const float*)d_in[4];
    const float* Wv1 = (const float*)d_in[5];
    const float* bv1 = (const float*)d_in[6];
    const float* Wq2 = (const float*)d_in[7];
    const float* bq2 = (const float*)d_in[8];
    const float* Wk2 = (const float*)d_in[9];
    const float* bk2 = (const float*)d_in[10];
    const float* Wv2 = (const float*)d_in[11];
    const float* bv2 = (const float*)d_in[12];
    const float* g1  = (const float*)d_in[13];
    const float* be1 = (const float*)d_in[14];
    const float* g2  = (const float*)d_in[15];
    const float* be2 = (const float*)d_in[16];

    const size_t NE = (size_t)16384 * 256;   // 4,194,304
    short* O1  = (short*)d_ws;               // 8 MB (layer-1 output, bf16)
    short* Wb  = O1 + NE;                    // 6 x 65536
    short* Qb  = Wb + 6 * 65536;
    short* Kb  = Qb + NE;
    short* VTb = Kb + NE;
    short* Op  = VTb + NE;                   // 4 x 16384 x 256 bf16 = 32 MB
    float* Lo  = (float*)(Op + 4 * NE);      // 4 x 16384 fp32
    float* outp = (float*)d_out;

    dim3 pgrid(256, 3), pblk(256);

    cvt_w_kernel<<<192, 256, 0, stream>>>(Wq1, Wk1, Wv1, Wq2, Wk2, Wv2, Wb);

    qkv_proj_kernel<float><<<pgrid, pblk, 0, stream>>>(
        x, Wb + 0 * 65536, bq1, Wb + 1 * 65536, bk1, Wb + 2 * 65536, bv1, Qb, Kb, VTb);
    attn_part_kernel<<<256, 512, 0, stream>>>(Qb, Kb, VTb, Op, Lo);
    merge_ln_kernel<float, short><<<4096, 256, 0, stream>>>(Op, Lo, x, g1, be1, O1);

    qkv_proj_kernel<short><<<pgrid, pblk, 0, stream>>>(
        O1, Wb + 3 * 65536, bq2, Wb + 4 * 65536, bk2, Wb + 5 * 65536, bv2, Qb, Kb, VTb);
    attn_part_kernel<<<256, 512, 0, stream>>>(Qb, Kb, VTb, Op, Lo);
    merge_ln_kernel<short, float><<<4096, 256, 0, stream>>>(Op, Lo, O1, g2, be2, outp);
}

// Round 8
// 360.404 us; speedup vs baseline: 1.8999x; 1.8999x over previous
//
#include <hip/hip_runtime.h>
#include <hip/hip_bf16.h>

// Block_45810121179249: 2x (single-head attn + residual + LayerNorm)
// B=4, S=4096, E=256. FP32 in/out; proj in bf16 MFMA; attention in fp8
// (e4m3 Q/K/V/P storage, f32 accumulation, fp8 MFMA at bf16 rate with 2x K).
//
// Round 8: attn redesign — 1 q-strip/wave (16 rows), 256-thr blocks, BK=32,
// K+V LDS double-buffered (1 barrier/tile), fp8 fragments (8 B/lane) halve
// LDS traffic; VGPR<=128 + LDS 35 KB -> 4 blocks/CU (16 waves, 4/SIMD).
// V back in LDS (round-7 global-V thrashed L2: FETCH 368 MB).

typedef __attribute__((ext_vector_type(8))) short bf16x8;
typedef __attribute__((ext_vector_type(4))) float f32x4;
typedef unsigned char u8;

#define MFMA_BF16(A, B, C) __builtin_amdgcn_mfma_f32_16x16x32_bf16(A, B, C, 0, 0, 0)
#define MFMA_FP8(A, B, C)  __builtin_amdgcn_mfma_f32_16x16x32_fp8_fp8(A, B, C, 0, 0, 0)

#define CP16(g, l)                                                              \
    __builtin_amdgcn_global_load_lds(                                           \
        (const __attribute__((address_space(1))) void*)(g),                     \
        (__attribute__((address_space(3))) void*)(l), 16, 0, 0)

static __device__ __forceinline__ short f2bf(float f) {
    __hip_bfloat16 h = __float2bfloat16(f);
    return __builtin_bit_cast(short, h);
}
static __device__ __forceinline__ float bf2f(short s) {
    unsigned int u = ((unsigned int)(unsigned short)s) << 16;
    return __builtin_bit_cast(float, u);
}
static __device__ __forceinline__ float ld1(const float* p) { return *p; }
static __device__ __forceinline__ float ld1(const short* p) { return bf2f(*p); }
static __device__ __forceinline__ void st1(float* p, float v) { *p = v; }
static __device__ __forceinline__ void st1(short* p, float v) { *p = f2bf(v); }

static __device__ __forceinline__ u8 f2fp8(float f) {
    return (u8)(__builtin_amdgcn_cvt_pk_fp8_f32(f, f, 0, false) & 0xff);
}
static __device__ __forceinline__ unsigned int pk4fp8(float a, float b, float c, float d) {
    int w = __builtin_amdgcn_cvt_pk_fp8_f32(a, b, 0, false);
    w = __builtin_amdgcn_cvt_pk_fp8_f32(c, d, w, true);
    return (unsigned int)w;
}

static __device__ __forceinline__ bf16x8 ldA8(const short* p) {
    return *reinterpret_cast<const bf16x8*>(p);
}
static __device__ __forceinline__ bf16x8 ldA8(const float* p) {
    float4 f0 = *reinterpret_cast<const float4*>(p);
    float4 f1 = *reinterpret_cast<const float4*>(p + 4);
    bf16x8 r;
    r[0] = f2bf(f0.x); r[1] = f2bf(f0.y); r[2] = f2bf(f0.z); r[3] = f2bf(f0.w);
    r[4] = f2bf(f1.x); r[5] = f2bf(f1.y); r[6] = f2bf(f1.z); r[7] = f2bf(f1.w);
    return r;
}

// ---- staging: proj W tiles (256 thr, bf16 rows of 512 B) -------------------
template <int NCH256>
static __device__ __forceinline__ void stage_rows(const short* __restrict__ g,
                                                  short* s, int tid) {
    const int wave = tid >> 6;
#pragma unroll
    for (int j = 0; j < NCH256; ++j) {
        const int idx = j * 256 + tid;
        const int row = idx >> 5, c = idx & 31;
        CP16(g + row * 256 + ((c ^ (row & 7)) << 3),
             s + ((j * 256 + wave * 64) << 3));
    }
}
// ---- staging: attn K tile (fp8, 32 keys x 256 B, chunk XOR by key&15) ------
static __device__ __forceinline__ void stage_k8(const u8* __restrict__ g,
                                                u8* s, int tid) {
    const int wave = tid >> 6;
#pragma unroll
    for (int j = 0; j < 2; ++j) {
        const int idx = j * 256 + tid;
        const int key = idx >> 4, c = idx & 15;
        CP16(g + key * 256 + ((c ^ (key & 15)) << 4),
             s + ((j * 256 + wave * 64) << 4));
    }
}
// ---- staging: attn V tile (fp8, 256 e-rows x 32 B, linear) -----------------
static __device__ __forceinline__ void stage_v8(const u8* __restrict__ g,
                                                u8* s, int tid) {
    const int wave = tid >> 6;
#pragma unroll
    for (int j = 0; j < 2; ++j) {
        const int idx = j * 256 + tid;
        const int e = idx >> 1, c = idx & 1;
        CP16(g + e * 4096 + (c << 4),
             s + ((j * 256 + wave * 64) << 4));
    }
}

// ---------------- fp32 -> bf16 weight conversion (6 x 65536) ----------------
__global__ __launch_bounds__(256) void cvt_w_kernel(
    const float* __restrict__ w0, const float* __restrict__ w1,
    const float* __restrict__ w2, const float* __restrict__ w3,
    const float* __restrict__ w4, const float* __restrict__ w5,
    short* __restrict__ wb)
{
    const int idx = (blockIdx.x * 256 + threadIdx.x) * 8;   // grid 192 -> exact
    const int w = idx >> 16, off = idx & 65535;
    const float* src = w0;
    if (w == 1) src = w1;
    else if (w == 2) src = w2;
    else if (w == 3) src = w3;
    else if (w == 4) src = w4;
    else if (w == 5) src = w5;
    *reinterpret_cast<bf16x8*>(wb + w * 65536 + off) = ldA8(src + off);
}

// ---------------- QKV projection (bf16 MFMA), outputs fp8 Q/K/VT ------------
template <typename TX>
__global__ __launch_bounds__(256, 2) void qkv_proj_kernel(
    const TX* __restrict__ X,
    const short* __restrict__ Wq, const float* __restrict__ bq,
    const short* __restrict__ Wk, const float* __restrict__ bk,
    const short* __restrict__ Wv, const float* __restrict__ bv,
    u8* __restrict__ Qo, u8* __restrict__ Ko, u8* __restrict__ VTo)
{
    __shared__ __attribute__((aligned(16))) short Wt[128 * 256];  // 64 KB half
    const int tid  = threadIdx.x;
    const int lane = tid & 63;
    const int wave = tid >> 6;
    const int c16  = lane & 15;
    const int quad = lane >> 4;
    const int which = blockIdx.y;
    const int m0 = blockIdx.x * 64 + wave * 16;

    const short* W    = (which == 0) ? Wq : (which == 1) ? Wk : Wv;
    const float* bias = (which == 0) ? bq : (which == 1) ? bk : bv;

    bf16x8 a[8];
#pragma unroll
    for (int ke = 0; ke < 8; ++ke)
        a[ke] = ldA8(X + (m0 + c16) * 256 + ke * 32 + quad * 8);

    f32x4 acc[16];
#pragma unroll
    for (int nb = 0; nb < 16; ++nb) { f32x4 z = {0.f, 0.f, 0.f, 0.f}; acc[nb] = z; }

#pragma unroll
    for (int half = 0; half < 2; ++half) {
        if (half) __syncthreads();
        stage_rows<16>(W + half * 128 * 256, Wt, tid);
        __syncthreads();
#pragma unroll
        for (int nb8 = 0; nb8 < 8; ++nb8) {
            const int nb = half * 8 + nb8;
            const short* wr = Wt + (nb8 * 16 + c16) * 256;
#pragma unroll
            for (int ke = 0; ke < 8; ++ke) {
                bf16x8 b = *reinterpret_cast<const bf16x8*>(
                    wr + (((ke * 4 + quad) ^ (c16 & 7)) << 3));
                acc[nb] = MFMA_BF16(a[ke], b, acc[nb]);
            }
        }
    }

    if (which < 2) {
        u8* dst = (which == 0) ? Qo : Ko;
#pragma unroll
        for (int nb = 0; nb < 16; ++nb) {
            const int o = nb * 16 + c16;
            const float bb_ = bias[o];
#pragma unroll
            for (int r = 0; r < 4; ++r)
                dst[(m0 + quad * 4 + r) * 256 + o] = f2fp8(acc[nb][r] + bb_);
        }
    } else {
        // transposed fp8 store: 4 consecutive tokens packed into one dword
#pragma unroll
        for (int nb = 0; nb < 16; ++nb) {
            const int o = nb * 16 + c16;
            const float bb_ = bias[o];
            const int row = m0 + quad * 4;
            const int batch = row >> 12;
            const int n = row & 4095;
            unsigned int pk = pk4fp8(acc[nb][0] + bb_, acc[nb][1] + bb_,
                                     acc[nb][2] + bb_, acc[nb][3] + bb_);
            *reinterpret_cast<unsigned int*>(
                VTo + (size_t)batch * (256 * 4096) + o * 4096 + n) = pk;
        }
    }
}

// ---------------- split-K flash attention partial (fp8) ---------------------
// grid 1024 = 64 qt x 16 (4 batch x 4 ks) x 2; combo = ((bi&7)<<1)|(bi>>9).
// Block: 256 thr = 4 waves x 16 q-rows = 64 rows; BK=32 keys/tile, 32 tiles.
// K,V fp8 double-buffered in LDS (8 KB each buf), 1 __syncthreads per tile.
// 4 blocks/CU co-resident (LDS 35 KB, VGPR<=128) -> 16 waves/CU.
__global__ __launch_bounds__(256, 4) void attn_part_kernel(
    const u8* __restrict__ Qb, const u8* __restrict__ Kb,
    const u8* __restrict__ VTb,
    short* __restrict__ Op, float* __restrict__ Lo)
{
    __shared__ __attribute__((aligned(16))) u8 Kt[2][32 * 256];   // 2x8 KB
    __shared__ __attribute__((aligned(16))) u8 Vt[2][256 * 32];   // 2x8 KB
    __shared__ __attribute__((aligned(16))) u8 Pb[4][16 * 48];    // 3 KB

    const int tid  = threadIdx.x;
    const int lane = tid & 63;
    const int wave = tid >> 6;
    const int c16  = lane & 15;
    const int quad = lane >> 4;
    const int bi = blockIdx.x;
    const int combo = ((bi & 7) << 1) | (bi >> 9);
    const int batch = combo >> 2;
    const int ks    = combo & 3;
    const int qt    = (bi >> 3) & 63;
    const size_t bb = (size_t)batch * (4096 * 256);
    const int rw = qt * 64 + wave * 16;           // wave's 16 q rows
    const int kbase = ks * 1024;

    // Q fragments fp8: 8 x 8 B = 16 VGPRs
    long qf[8];
#pragma unroll
    for (int ke = 0; ke < 8; ++ke)
        qf[ke] = *reinterpret_cast<const long*>(
            Qb + bb + (rw + c16) * 256 + ke * 32 + quad * 8);

    f32x4 oa[16];
#pragma unroll
    for (int nb = 0; nb < 16; ++nb) { f32x4 z = {0.f, 0.f, 0.f, 0.f}; oa[nb] = z; }
    float lsum[4] = {0.f, 0.f, 0.f, 0.f};

    constexpr float K1 = 1.4426950408889634f / 64.0f;  // log2(e)/sqrt(4096)
    u8* pw = &Pb[wave][0];

    stage_k8(Kb + bb + kbase * 256, &Kt[0][0], tid);
    stage_v8(VTb + bb + kbase, &Vt[0][0], tid);

    for (int kt = 0; kt < 32; ++kt) {
        __syncthreads();   // tile kt staged; slot (kt+1)&1 free
        if (kt + 1 < 32) {
            stage_k8(Kb + bb + (kbase + (kt + 1) * 32) * 256, &Kt[(kt + 1) & 1][0], tid);
            stage_v8(VTb + bb + kbase + (kt + 1) * 32, &Vt[(kt + 1) & 1][0], tid);
        }
        const u8* K = &Kt[kt & 1][0];
        const u8* V = &Vt[kt & 1][0];

        // ---- S = Q K^T : 2 key-blocks x 8 e-steps (K=32 each) ----
        f32x4 s[2];
        { f32x4 z = {0.f, 0.f, 0.f, 0.f}; s[0] = z; s[1] = z; }
#pragma unroll
        for (int nb = 0; nb < 2; ++nb) {
            const u8* kr = K + (nb * 16 + c16) * 256;
#pragma unroll
            for (int ke = 0; ke < 8; ++ke) {
                long kf = *reinterpret_cast<const long*>(
                    kr + (((ke * 2 + (quad >> 1)) ^ c16) << 4) + (quad & 1) * 8);
                s[nb] = MFMA_FP8(qf[ke], kf, s[nb]);
            }
        }

        // ---- p = exp2(z*K1); per-lane l; P -> wave-private LDS (fp8) ----
#pragma unroll
        for (int nb = 0; nb < 2; ++nb) {
#pragma unroll
            for (int r = 0; r < 4; ++r) {
                const float pv = exp2f(s[nb][r] * K1);
                lsum[r] += pv;
                pw[(quad * 4 + r) * 48 + nb * 16 + c16] = f2fp8(pv);
            }
        }
        long ap = *reinterpret_cast<const long*>(pw + c16 * 48 + quad * 8);

        // ---- O += P V : 16 e-blocks, K=32 keys each ----
#pragma unroll
        for (int nb = 0; nb < 16; ++nb) {
            long v = *reinterpret_cast<const long*>(V + (nb * 16 + c16) * 32 + quad * 8);
            oa[nb] = MFMA_FP8(ap, v, oa[nb]);
        }
    }

    // ---- reduce l across the 16 key-lanes; write bf16 partials ----
#pragma unroll
    for (int r = 0; r < 4; ++r) {
        float rs = lsum[r];
        rs += __shfl_xor(rs, 1, 64);
        rs += __shfl_xor(rs, 2, 64);
        rs += __shfl_xor(rs, 4, 64);
        rs += __shfl_xor(rs, 8, 64);
        const int grow = rw + quad * 4 + r;
        const size_t ridx = (size_t)ks * 16384 + batch * 4096 + grow;
#pragma unroll
        for (int nb = 0; nb < 16; ++nb)
            Op[ridx * 256 + nb * 16 + c16] = f2bf(oa[nb][r]);
        if (c16 == 0) Lo[ridx] = rs;
    }
}

// ---------------- merge splits + residual + LayerNorm ----------------
template <typename TRES, typename TOUT>
__global__ __launch_bounds__(256) void merge_ln_kernel(
    const short* __restrict__ Op, const float* __restrict__ Lo,
    const TRES* __restrict__ res, const float* __restrict__ gamma,
    const float* __restrict__ beta, TOUT* __restrict__ out)
{
    const int lane = threadIdx.x & 63;
    const int wave = threadIdx.x >> 6;
    const int row = blockIdx.x * 4 + wave;          // batch*4096 + local row
    const float li = 1.0f / (Lo[row] + Lo[16384 + row] +
                             Lo[32768 + row] + Lo[49152 + row]);
    const int e = lane * 4;
    float o[4] = {0.f, 0.f, 0.f, 0.f};
#pragma unroll
    for (int s = 0; s < 4; ++s) {
        ushort4 u = *reinterpret_cast<const ushort4*>(
            Op + ((size_t)s * 16384 + row) * 256 + e);
        o[0] += bf2f((short)u.x);
        o[1] += bf2f((short)u.y);
        o[2] += bf2f((short)u.z);
        o[3] += bf2f((short)u.w);
    }
    float y[4];
#pragma unroll
    for (int i = 0; i < 4; ++i)
        y[i] = o[i] * li + ld1(res + (size_t)row * 256 + e + i);

    float sum = y[0] + y[1] + y[2] + y[3];
    float sq  = y[0]*y[0] + y[1]*y[1] + y[2]*y[2] + y[3]*y[3];
#pragma unroll
    for (int d = 1; d < 64; d <<= 1) {
        sum += __shfl_xor(sum, d, 64);
        sq  += __shfl_xor(sq,  d, 64);
    }
    const float mean = sum * (1.0f / 256.0f);
    const float var  = sq * (1.0f / 256.0f) - mean * mean;
    const float rstd = rsqrtf(var + 1e-5f);
#pragma unroll
    for (int i = 0; i < 4; ++i)
        st1(out + (size_t)row * 256 + e + i,
            (y[i] - mean) * rstd * gamma[e + i] + beta[e + i]);
}

extern "C" void kernel_launch(void* const* d_in, const int* in_sizes, int n_in,
                              void* d_out, int out_size, void* d_ws, size_t ws_size,
                              hipStream_t stream) {
    const float* x   = (const float*)d_in[0];
    const float* Wq1 = (const float*)d_in[1];
    const float* bq1 = (const float*)d_in[2];
    const float* Wk1 = (const float*)d_in[3];
    const float* bk1 = (const float*)d_in[4];
    const float* Wv1 = (const float*)d_in[5];
    const float* bv1 = (const float*)d_in[6];
    const float* Wq2 = (const float*)d_in[7];
    const float* bq2 = (const float*)d_in[8];
    const float* Wk2 = (const float*)d_in[9];
    const float* bk2 = (const float*)d_in[10];
    const float* Wv2 = (const float*)d_in[11];
    const float* bv2 = (const float*)d_in[12];
    const float* g1  = (const float*)d_in[13];
    const float* be1 = (const float*)d_in[14];
    const float* g2  = (const float*)d_in[15];
    const float* be2 = (const float*)d_in[16];

    const size_t NE = (size_t)16384 * 256;   // 4,194,304
    short* O1  = (short*)d_ws;               // 8 MB (layer-1 output, bf16)
    short* Wb  = O1 + NE;                    // 6 x 65536 bf16
    u8*    Qb  = (u8*)(Wb + 6 * 65536);      // fp8, 4 MB
    u8*    Kb  = Qb + NE;                    // fp8, 4 MB
    u8*    VTb = Kb + NE;                    // fp8, 4 MB
    short* Op  = (short*)(VTb + NE);         // 4 x 16384 x 256 bf16 = 32 MB
    float* Lo  = (float*)(Op + 4 * NE);      // 4 x 16384 fp32
    float* outp = (float*)d_out;

    dim3 pgrid(256, 3), pblk(256);

    cvt_w_kernel<<<192, 256, 0, stream>>>(Wq1, Wk1, Wv1, Wq2, Wk2, Wv2, Wb);

    qkv_proj_kernel<float><<<pgrid, pblk, 0, stream>>>(
        x, Wb + 0 * 65536, bq1, Wb + 1 * 65536, bk1, Wb + 2 * 65536, bv1, Qb, Kb, VTb);
    attn_part_kernel<<<1024, 256, 0, stream>>>(Qb, Kb, VTb, Op, Lo);
    merge_ln_kernel<float, short><<<4096, 256, 0, stream>>>(Op, Lo, x, g1, be1, O1);

    qkv_proj_kernel<short><<<pgrid, pblk, 0, stream>>>(
        O1, Wb + 3 * 65536, bq2, Wb + 4 * 65536, bk2, Wb + 5 * 65536, bv2, Qb, Kb, VTb);
    attn_part_kernel<<<1024, 256, 0, stream>>>(Qb, Kb, VTb, Op, Lo);
    merge_ln_kernel<short, float><<<4096, 256, 0, stream>>>(Op, Lo, O1, g2, be2, outp);
}

// Round 10
// 310.926 us; speedup vs baseline: 2.2022x; 1.1591x over previous
//
#include <hip/hip_runtime.h>
#include <hip/hip_bf16.h>

// Block_45810121179249: 2x (single-head attn + residual + LayerNorm)
// B=4, S=4096, E=256. FP32 in/out; proj bf16 MFMA; attention fp8 MFMA.
//
// Round 10: round-9 structure with the TBAA bug fixed — P is written as
// unsigned int (pk4fp8) and now READ BACK as unsigned int too (ds_read2),
// assembled into the i64 MFMA operand by bit_cast. (Round 9 read via long*
// -> strict aliasing let the compiler break the write->read ordering ->
// uninitialized-LDS fp8 NaNs.)
//  - S^T trick: QK as MFMA(K,Q): lane holds 4 consecutive keys of one q-row
//    -> P packed to dwords; l-sum is one scalar/lane (xor16/32 at end).
//  - V tile swizzle slot=2e+(h^((e>>2)&1)): 2 lanes/bank per half-wave.
//  - P rows stride 40 B; K chunk-XOR swizzle; all DS conflict-free.
//  - 2 q-strips/wave; 512 blocks = 2/CU; K,V fp8 double-buffered, 1 barrier.
//  - fused QKV projection (X read once).

typedef __attribute__((ext_vector_type(8))) short bf16x8;
typedef __attribute__((ext_vector_type(4))) float f32x4;
typedef __attribute__((ext_vector_type(2))) unsigned int u32x2;
typedef unsigned char u8;

#define MFMA_BF16(A, B, C) __builtin_amdgcn_mfma_f32_16x16x32_bf16(A, B, C, 0, 0, 0)
#define MFMA_FP8(A, B, C)  __builtin_amdgcn_mfma_f32_16x16x32_fp8_fp8(A, B, C, 0, 0, 0)

#define CP16(g, l)                                                              \
    __builtin_amdgcn_global_load_lds(                                           \
        (const __attribute__((address_space(1))) void*)(g),                     \
        (__attribute__((address_space(3))) void*)(l), 16, 0, 0)

static __device__ __forceinline__ short f2bf(float f) {
    __hip_bfloat16 h = __float2bfloat16(f);
    return __builtin_bit_cast(short, h);
}
static __device__ __forceinline__ float bf2f(short s) {
    unsigned int u = ((unsigned int)(unsigned short)s) << 16;
    return __builtin_bit_cast(float, u);
}
static __device__ __forceinline__ float ld1(const float* p) { return *p; }
static __device__ __forceinline__ float ld1(const short* p) { return bf2f(*p); }
static __device__ __forceinline__ void st1(float* p, float v) { *p = v; }
static __device__ __forceinline__ void st1(short* p, float v) { *p = f2bf(v); }

static __device__ __forceinline__ u8 f2fp8(float f) {
    return (u8)(__builtin_amdgcn_cvt_pk_fp8_f32(f, f, 0, false) & 0xff);
}
static __device__ __forceinline__ unsigned int pk4fp8(float a, float b, float c, float d) {
    int w = __builtin_amdgcn_cvt_pk_fp8_f32(a, b, 0, false);
    w = __builtin_amdgcn_cvt_pk_fp8_f32(c, d, w, true);
    return (unsigned int)w;
}

static __device__ __forceinline__ bf16x8 ldA8(const short* p) {
    return *reinterpret_cast<const bf16x8*>(p);
}
static __device__ __forceinline__ bf16x8 ldA8(const float* p) {
    float4 f0 = *reinterpret_cast<const float4*>(p);
    float4 f1 = *reinterpret_cast<const float4*>(p + 4);
    bf16x8 r;
    r[0] = f2bf(f0.x); r[1] = f2bf(f0.y); r[2] = f2bf(f0.z); r[3] = f2bf(f0.w);
    r[4] = f2bf(f1.x); r[5] = f2bf(f1.y); r[6] = f2bf(f1.z); r[7] = f2bf(f1.w);
    return r;
}

// ---- staging: proj W tiles (256 thr, bf16 rows of 512 B) -------------------
template <int NCH256>
static __device__ __forceinline__ void stage_rows(const short* __restrict__ g,
                                                  short* s, int tid) {
    const int wave = tid >> 6;
#pragma unroll
    for (int j = 0; j < NCH256; ++j) {
        const int idx = j * 256 + tid;
        const int row = idx >> 5, c = idx & 31;
        CP16(g + row * 256 + ((c ^ (row & 7)) << 3),
             s + ((j * 256 + wave * 64) << 3));
    }
}
// ---- staging: attn K tile (fp8, 32 keys x 256 B, chunk XOR by key&15) ------
static __device__ __forceinline__ void stage_k8(const u8* __restrict__ g,
                                                u8* s, int tid) {
    const int wave = tid >> 6;
#pragma unroll
    for (int j = 0; j < 2; ++j) {
        const int idx = j * 256 + tid;
        const int key = idx >> 4, c = idx & 15;
        CP16(g + key * 256 + ((c ^ (key & 15)) << 4),
             s + ((j * 256 + wave * 64) << 4));
    }
}
// ---- staging: attn V tile (fp8, 256 e x 32 keys): slot = 2e+(h^((e>>2)&1)) -
static __device__ __forceinline__ void stage_v8(const u8* __restrict__ g,
                                                u8* s, int tid) {
    const int wave = tid >> 6;
#pragma unroll
    for (int j = 0; j < 2; ++j) {
        const int idx = j * 256 + tid;
        const int e = idx >> 1;
        const int h = (idx & 1) ^ ((idx >> 3) & 1);
        CP16(g + e * 4096 + h * 16,
             s + ((j * 256 + wave * 64) << 4));
    }
}

// ---------------- fp32 -> bf16 weight conversion (6 x 65536) ----------------
__global__ __launch_bounds__(256) void cvt_w_kernel(
    const float* __restrict__ w0, const float* __restrict__ w1,
    const float* __restrict__ w2, const float* __restrict__ w3,
    const float* __restrict__ w4, const float* __restrict__ w5,
    short* __restrict__ wb)
{
    const int idx = (blockIdx.x * 256 + threadIdx.x) * 8;   // grid 192 -> exact
    const int w = idx >> 16, off = idx & 65535;
    const float* src = w0;
    if (w == 1) src = w1;
    else if (w == 2) src = w2;
    else if (w == 3) src = w3;
    else if (w == 4) src = w4;
    else if (w == 5) src = w5;
    *reinterpret_cast<bf16x8*>(wb + w * 65536 + off) = ldA8(src + off);
}

// ---------------- fused QKV projection (bf16 MFMA), fp8 outputs -------------
// grid 256: 64-row token tiles; X A-fragments loaded once, 3 weight loops.
template <typename TX>
__global__ __launch_bounds__(256) void qkv_proj_kernel(
    const TX* __restrict__ X, const short* __restrict__ Wb,
    const float* __restrict__ bq, const float* __restrict__ bk,
    const float* __restrict__ bv,
    u8* __restrict__ Qo, u8* __restrict__ Ko, u8* __restrict__ VTo)
{
    __shared__ __attribute__((aligned(16))) short Wt[128 * 256];  // 64 KB half
    const int tid  = threadIdx.x;
    const int lane = tid & 63;
    const int wave = tid >> 6;
    const int c16  = lane & 15;
    const int quad = lane >> 4;
    const int m0 = blockIdx.x * 64 + wave * 16;

    bf16x8 a[8];
#pragma unroll
    for (int ke = 0; ke < 8; ++ke)
        a[ke] = ldA8(X + (m0 + c16) * 256 + ke * 32 + quad * 8);

    for (int which = 0; which < 3; ++which) {
        const short* W = Wb + which * 65536;
        const float* bias = (which == 0) ? bq : (which == 1) ? bk : bv;

        f32x4 acc[16];
#pragma unroll
        for (int nb = 0; nb < 16; ++nb) { f32x4 z = {0.f, 0.f, 0.f, 0.f}; acc[nb] = z; }

        for (int half = 0; half < 2; ++half) {
            __syncthreads();                   // prior reads of Wt done
            stage_rows<16>(W + half * 128 * 256, Wt, tid);
            __syncthreads();                   // tile ready
#pragma unroll
            for (int nb8 = 0; nb8 < 8; ++nb8) {
                const int nb = half * 8 + nb8;
                const short* wr = Wt + (nb8 * 16 + c16) * 256;
#pragma unroll
                for (int ke = 0; ke < 8; ++ke) {
                    bf16x8 b = *reinterpret_cast<const bf16x8*>(
                        wr + (((ke * 4 + quad) ^ (c16 & 7)) << 3));
                    acc[nb] = MFMA_BF16(a[ke], b, acc[nb]);
                }
            }
        }

        if (which < 2) {
            u8* dst = (which == 0) ? Qo : Ko;
#pragma unroll
            for (int nb = 0; nb < 16; ++nb) {
                const int o = nb * 16 + c16;
                const float bb_ = bias[o];
#pragma unroll
                for (int r = 0; r < 4; ++r)
                    dst[(m0 + quad * 4 + r) * 256 + o] = f2fp8(acc[nb][r] + bb_);
            }
        } else {
#pragma unroll
            for (int nb = 0; nb < 16; ++nb) {
                const int o = nb * 16 + c16;
                const float bb_ = bias[o];
                const int row = m0 + quad * 4;
                const int batch = row >> 12;
                const int n = row & 4095;
                unsigned int pk = pk4fp8(acc[nb][0] + bb_, acc[nb][1] + bb_,
                                         acc[nb][2] + bb_, acc[nb][3] + bb_);
                *reinterpret_cast<unsigned int*>(
                    VTo + (size_t)batch * (256 * 4096) + o * 4096 + n) = pk;
            }
        }
    }
}

// ---------------- split-K flash attention partial (fp8, conflict-free) ------
// grid 512: combo = ((bi&7)<<1)|(bi>>8) -> 2 (batch,ks) pairs per XCD (L2-
// local, 1 MB); qt = (bi>>3)&31. Block 256 thr = 4 waves x 32 q-rows
// (2 strips of 16); BK=32 keys/tile, 32 tiles; K,V fp8 double-buffered.
__global__ __launch_bounds__(256, 2) void attn_part_kernel(
    const u8* __restrict__ Qb, const u8* __restrict__ Kb,
    const u8* __restrict__ VTb,
    short* __restrict__ Op, float* __restrict__ Lo)
{
    __shared__ __attribute__((aligned(16))) u8 Kt[2][32 * 256];   // 2x8 KB
    __shared__ __attribute__((aligned(16))) u8 Vt[2][256 * 32];   // 2x8 KB
    __shared__ __attribute__((aligned(16))) u8 Pb[4][32 * 40];    // 5 KB

    const int tid  = threadIdx.x;
    const int lane = tid & 63;
    const int wave = tid >> 6;
    const int c16  = lane & 15;
    const int quad = lane >> 4;
    const int iq   = quad & 1;
    const int qh   = quad >> 1;
    const int bi = blockIdx.x;
    const int combo = ((bi & 7) << 1) | (bi >> 8);
    const int batch = combo >> 2;
    const int ks    = combo & 3;
    const int qt    = (bi >> 3) & 31;
    const size_t bb = (size_t)batch * (4096 * 256);
    const int rw = qt * 128 + wave * 32;          // wave's 32 q rows
    const int kbase = ks * 1024;

    // Q B-fragments (for S^T = K Q^T): Q[qrow=c16][e], 8 B x 8 x 2 strips
    long qf[2][8];
#pragma unroll
    for (int t = 0; t < 2; ++t)
#pragma unroll
        for (int ke = 0; ke < 8; ++ke)
            qf[t][ke] = *reinterpret_cast<const long*>(
                Qb + bb + (rw + t * 16 + c16) * 256 + ke * 32 + quad * 8);

    f32x4 oa[2][16];
#pragma unroll
    for (int t = 0; t < 2; ++t)
#pragma unroll
        for (int nb = 0; nb < 16; ++nb) { f32x4 z = {0.f, 0.f, 0.f, 0.f}; oa[t][nb] = z; }
    float lsum[2] = {0.f, 0.f};

    constexpr float K1 = 1.4426950408889634f / 64.0f;  // log2(e)/sqrt(4096)
    u8* pw = &Pb[wave][0];
    // u32 view of the wave's P buffer: row stride 10 dwords (40 B)
    unsigned int* pw32 = reinterpret_cast<unsigned int*>(pw);

    // lane-constant LDS offsets (hoisted; per-read addr = base + imm only)
    int kx[8];
#pragma unroll
    for (int ke = 0; ke < 8; ++ke)
        kx[ke] = ((ke * 2 + qh) ^ c16) << 4;
    const int kroff = c16 * 256 + iq * 8;
    const int voff  = c16 * 32 + ((qh ^ ((c16 >> 2) & 1)) << 4) + iq * 8;

    const u8* Kg = Kb + bb + kbase * 256;
    const u8* Vg = VTb + bb + kbase;

    stage_k8(Kg, &Kt[0][0], tid);
    stage_v8(Vg, &Vt[0][0], tid);

    for (int kt = 0; kt < 32; ++kt) {
        __syncthreads();   // tile kt staged; slot (kt+1)&1 free
        if (kt + 1 < 32) {
            stage_k8(Kg + (kt + 1) * 32 * 256, &Kt[(kt + 1) & 1][0], tid);
            stage_v8(Vg + (kt + 1) * 32, &Vt[(kt + 1) & 1][0], tid);
        }
        const u8* K = &Kt[kt & 1][0];
        const u8* V = &Vt[kt & 1][0];

        // ---- S^T = K Q^T : rows=keys, cols=qrows; K frag shared by strips --
        f32x4 s[2][2];
        { f32x4 z = {0.f, 0.f, 0.f, 0.f}; s[0][0]=z; s[0][1]=z; s[1][0]=z; s[1][1]=z; }
#pragma unroll
        for (int nb = 0; nb < 2; ++nb) {
#pragma unroll
            for (int ke = 0; ke < 8; ++ke) {
                long kf = *reinterpret_cast<const long*>(K + kroff + kx[ke] + nb * 4096);
                s[0][nb] = MFMA_FP8(kf, qf[0][ke], s[0][nb]);
                s[1][nb] = MFMA_FP8(kf, qf[1][ke], s[1][nb]);
            }
        }

        // ---- p = exp2(z*K1): lane holds 4 consecutive keys of qrow c16 ----
#pragma unroll
        for (int t = 0; t < 2; ++t) {
#pragma unroll
            for (int nb = 0; nb < 2; ++nb) {
                const float p0 = exp2f(s[t][nb][0] * K1);
                const float p1 = exp2f(s[t][nb][1] * K1);
                const float p2 = exp2f(s[t][nb][2] * K1);
                const float p3 = exp2f(s[t][nb][3] * K1);
                lsum[t] += (p0 + p1) + (p2 + p3);
                pw32[(t * 16 + c16) * 10 + nb * 4 + quad] = pk4fp8(p0, p1, p2, p3);
            }
        }
        // read back through the SAME scalar type (u32) -> TBAA-safe ordering;
        // adjacent pairs merge to ds_read2_b32; bit_cast pairs into i64.
        u32x2 aw0, aw1;
        aw0.x = pw32[c16 * 10 + quad * 2];
        aw0.y = pw32[c16 * 10 + quad * 2 + 1];
        aw1.x = pw32[(16 + c16) * 10 + quad * 2];
        aw1.y = pw32[(16 + c16) * 10 + quad * 2 + 1];
        long ap0 = __builtin_bit_cast(long, aw0);
        long ap1 = __builtin_bit_cast(long, aw1);

        // ---- O += P V : V frag shared by both strips ----
#pragma unroll
        for (int nb = 0; nb < 16; ++nb) {
            long v = *reinterpret_cast<const long*>(V + voff + nb * 512);
            oa[0][nb] = MFMA_FP8(ap0, v, oa[0][nb]);
            oa[1][nb] = MFMA_FP8(ap1, v, oa[1][nb]);
        }
    }

    // ---- l: reduce across quads (keys live on lane bits 4,5) ----
#pragma unroll
    for (int t = 0; t < 2; ++t) {
        float rs = lsum[t];
        rs += __shfl_xor(rs, 16, 64);
        rs += __shfl_xor(rs, 32, 64);
        const size_t base = (size_t)ks * 16384 + batch * 4096 + rw + t * 16;
#pragma unroll
        for (int nb = 0; nb < 16; ++nb)
#pragma unroll
            for (int r = 0; r < 4; ++r)
                Op[(base + quad * 4 + r) * 256 + nb * 16 + c16] = f2bf(oa[t][nb][r]);
        if (lane < 16) Lo[base + c16] = rs;
    }
}

// ---------------- merge splits + residual + LayerNorm ----------------
template <typename TRES, typename TOUT>
__global__ __launch_bounds__(256) void merge_ln_kernel(
    const short* __restrict__ Op, const float* __restrict__ Lo,
    const TRES* __restrict__ res, const float* __restrict__ gamma,
    const float* __restrict__ beta, TOUT* __restrict__ out)
{
    const int lane = threadIdx.x & 63;
    const int wave = threadIdx.x >> 6;
    const int row = blockIdx.x * 4 + wave;          // batch*4096 + local row
    const float li = 1.0f / (Lo[row] + Lo[16384 + row] +
                             Lo[32768 + row] + Lo[49152 + row]);
    const int e = lane * 4;
    float o[4] = {0.f, 0.f, 0.f, 0.f};
#pragma unroll
    for (int s = 0; s < 4; ++s) {
        ushort4 u = *reinterpret_cast<const ushort4*>(
            Op + ((size_t)s * 16384 + row) * 256 + e);
        o[0] += bf2f((short)u.x);
        o[1] += bf2f((short)u.y);
        o[2] += bf2f((short)u.z);
        o[3] += bf2f((short)u.w);
    }
    float y[4];
#pragma unroll
    for (int i = 0; i < 4; ++i)
        y[i] = o[i] * li + ld1(res + (size_t)row * 256 + e + i);

    float sum = y[0] + y[1] + y[2] + y[3];
    float sq  = y[0]*y[0] + y[1]*y[1] + y[2]*y[2] + y[3]*y[3];
#pragma unroll
    for (int d = 1; d < 64; d <<= 1) {
        sum += __shfl_xor(sum, d, 64);
        sq  += __shfl_xor(sq,  d, 64);
    }
    const float mean = sum * (1.0f / 256.0f);
    const float var  = sq * (1.0f / 256.0f) - mean * mean;
    const float rstd = rsqrtf(var + 1e-5f);
#pragma unroll
    for (int i = 0; i < 4; ++i)
        st1(out + (size_t)row * 256 + e + i,
            (y[i] - mean) * rstd * gamma[e + i] + beta[e + i]);
}

extern "C" void kernel_launch(void* const* d_in, const int* in_sizes, int n_in,
                              void* d_out, int out_size, void* d_ws, size_t ws_size,
                              hipStream_t stream) {
    const float* x   = (const float*)d_in[0];
    const float* Wq1 = (const float*)d_in[1];
    const float* bq1 = (const float*)d_in[2];
    const float* Wk1 = (const float*)d_in[3];
    const float* bk1 = (const float*)d_in[4];
    const float* Wv1 = (const float*)d_in[5];
    const float* bv1 = (const float*)d_in[6];
    const float* Wq2 = (const float*)d_in[7];
    const float* bq2 = (const float*)d_in[8];
    const float* Wk2 = (const float*)d_in[9];
    const float* bk2 = (const float*)d_in[10];
    const float* Wv2 = (const float*)d_in[11];
    const float* bv2 = (const float*)d_in[12];
    const float* g1  = (const float*)d_in[13];
    const float* be1 = (const float*)d_in[14];
    const float* g2  = (const float*)d_in[15];
    const float* be2 = (const float*)d_in[16];

    const size_t NE = (size_t)16384 * 256;   // 4,194,304
    short* O1  = (short*)d_ws;               // 8 MB (layer-1 output, bf16)
    short* Wb  = O1 + NE;                    // 6 x 65536 bf16
    u8*    Qb  = (u8*)(Wb + 6 * 65536);      // fp8, 4 MB
    u8*    Kb  = Qb + NE;                    // fp8, 4 MB
    u8*    VTb = Kb + NE;                    // fp8, 4 MB
    short* Op  = (short*)(VTb + NE);         // 4 x 16384 x 256 bf16 = 32 MB
    float* Lo  = (float*)(Op + 4 * NE);      // 4 x 16384 fp32
    float* outp = (float*)d_out;

    cvt_w_kernel<<<192, 256, 0, stream>>>(Wq1, Wk1, Wv1, Wq2, Wk2, Wv2, Wb);

    qkv_proj_kernel<float><<<256, 256, 0, stream>>>(
        x, Wb, bq1, bk1, bv1, Qb, Kb, VTb);
    attn_part_kernel<<<512, 256, 0, stream>>>(Qb, Kb, VTb, Op, Lo);
    merge_ln_kernel<float, short><<<4096, 256, 0, stream>>>(Op, Lo, x, g1, be1, O1);

    qkv_proj_kernel<short><<<256, 256, 0, stream>>>(
        O1, Wb + 3 * 65536, bq2, bk2, bv2, Qb, Kb, VTb);
    attn_part_kernel<<<512, 256, 0, stream>>>(Qb, Kb, VTb, Op, Lo);
    merge_ln_kernel<short, float><<<4096, 256, 0, stream>>>(Op, Lo, O1, g2, be2, outp);
}

// Round 11
// 300.280 us; speedup vs baseline: 2.2803x; 1.0355x over previous
//
#include <hip/hip_runtime.h>
#include <hip/hip_bf16.h>

// Block_45810121179249: 2x (single-head attn + residual + LayerNorm)
// B=4, S=4096, E=256. FP32 in/out; proj bf16 MFMA; attention fp8 MFMA.
//
// Round 11: round-8's high-occupancy attention shape (1 q-strip/wave, 256-thr
// blocks, grid 1024 -> 4 blocks/CU, 16 waves/CU) combined with round-10's
// conflict-free layouts (S^T trick + dword-packed P @ stride-40, V swizzle
// slot=2e+(h^((e>>2)&1)), K chunk-XOR, TBAA-safe u32 P readback).
// Projection un-fused (round-10 fusion serialized it: rest 124->153 us):
// grid (256,3), 3 concurrent blocks/CU.

typedef __attribute__((ext_vector_type(8))) short bf16x8;
typedef __attribute__((ext_vector_type(4))) float f32x4;
typedef __attribute__((ext_vector_type(2))) unsigned int u32x2;
typedef unsigned char u8;

#define MFMA_BF16(A, B, C) __builtin_amdgcn_mfma_f32_16x16x32_bf16(A, B, C, 0, 0, 0)
#define MFMA_FP8(A, B, C)  __builtin_amdgcn_mfma_f32_16x16x32_fp8_fp8(A, B, C, 0, 0, 0)

#define CP16(g, l)                                                              \
    __builtin_amdgcn_global_load_lds(                                           \
        (const __attribute__((address_space(1))) void*)(g),                     \
        (__attribute__((address_space(3))) void*)(l), 16, 0, 0)

static __device__ __forceinline__ short f2bf(float f) {
    __hip_bfloat16 h = __float2bfloat16(f);
    return __builtin_bit_cast(short, h);
}
static __device__ __forceinline__ float bf2f(short s) {
    unsigned int u = ((unsigned int)(unsigned short)s) << 16;
    return __builtin_bit_cast(float, u);
}
static __device__ __forceinline__ float ld1(const float* p) { return *p; }
static __device__ __forceinline__ float ld1(const short* p) { return bf2f(*p); }
static __device__ __forceinline__ void st1(float* p, float v) { *p = v; }
static __device__ __forceinline__ void st1(short* p, float v) { *p = f2bf(v); }

static __device__ __forceinline__ u8 f2fp8(float f) {
    return (u8)(__builtin_amdgcn_cvt_pk_fp8_f32(f, f, 0, false) & 0xff);
}
static __device__ __forceinline__ unsigned int pk4fp8(float a, float b, float c, float d) {
    int w = __builtin_amdgcn_cvt_pk_fp8_f32(a, b, 0, false);
    w = __builtin_amdgcn_cvt_pk_fp8_f32(c, d, w, true);
    return (unsigned int)w;
}

static __device__ __forceinline__ bf16x8 ldA8(const short* p) {
    return *reinterpret_cast<const bf16x8*>(p);
}
static __device__ __forceinline__ bf16x8 ldA8(const float* p) {
    float4 f0 = *reinterpret_cast<const float4*>(p);
    float4 f1 = *reinterpret_cast<const float4*>(p + 4);
    bf16x8 r;
    r[0] = f2bf(f0.x); r[1] = f2bf(f0.y); r[2] = f2bf(f0.z); r[3] = f2bf(f0.w);
    r[4] = f2bf(f1.x); r[5] = f2bf(f1.y); r[6] = f2bf(f1.z); r[7] = f2bf(f1.w);
    return r;
}

// ---- staging: proj W tiles (256 thr, bf16 rows of 512 B) -------------------
template <int NCH256>
static __device__ __forceinline__ void stage_rows(const short* __restrict__ g,
                                                  short* s, int tid) {
    const int wave = tid >> 6;
#pragma unroll
    for (int j = 0; j < NCH256; ++j) {
        const int idx = j * 256 + tid;
        const int row = idx >> 5, c = idx & 31;
        CP16(g + row * 256 + ((c ^ (row & 7)) << 3),
             s + ((j * 256 + wave * 64) << 3));
    }
}
// ---- staging: attn K tile (fp8, 32 keys x 256 B, chunk XOR by key&15) ------
static __device__ __forceinline__ void stage_k8(const u8* __restrict__ g,
                                                u8* s, int tid) {
    const int wave = tid >> 6;
#pragma unroll
    for (int j = 0; j < 2; ++j) {
        const int idx = j * 256 + tid;
        const int key = idx >> 4, c = idx & 15;
        CP16(g + key * 256 + ((c ^ (key & 15)) << 4),
             s + ((j * 256 + wave * 64) << 4));
    }
}
// ---- staging: attn V tile (fp8, 256 e x 32 keys): slot = 2e+(h^((e>>2)&1)) -
static __device__ __forceinline__ void stage_v8(const u8* __restrict__ g,
                                                u8* s, int tid) {
    const int wave = tid >> 6;
#pragma unroll
    for (int j = 0; j < 2; ++j) {
        const int idx = j * 256 + tid;
        const int e = idx >> 1;
        const int h = (idx & 1) ^ ((idx >> 3) & 1);
        CP16(g + e * 4096 + h * 16,
             s + ((j * 256 + wave * 64) << 4));
    }
}

// ---------------- fp32 -> bf16 weight conversion (6 x 65536) ----------------
__global__ __launch_bounds__(256) void cvt_w_kernel(
    const float* __restrict__ w0, const float* __restrict__ w1,
    const float* __restrict__ w2, const float* __restrict__ w3,
    const float* __restrict__ w4, const float* __restrict__ w5,
    short* __restrict__ wb)
{
    const int idx = (blockIdx.x * 256 + threadIdx.x) * 8;   // grid 192 -> exact
    const int w = idx >> 16, off = idx & 65535;
    const float* src = w0;
    if (w == 1) src = w1;
    else if (w == 2) src = w2;
    else if (w == 3) src = w3;
    else if (w == 4) src = w4;
    else if (w == 5) src = w5;
    *reinterpret_cast<bf16x8*>(wb + w * 65536 + off) = ldA8(src + off);
}

// ---------------- QKV projection (bf16 MFMA), fp8 outputs, un-fused ---------
// grid (256, 3): x = 64-row token tile, y = {Q,K,V}. 3 concurrent blocks/CU.
template <typename TX>
__global__ __launch_bounds__(256, 2) void qkv_proj_kernel(
    const TX* __restrict__ X, const short* __restrict__ Wb,
    const float* __restrict__ bq, const float* __restrict__ bk,
    const float* __restrict__ bv,
    u8* __restrict__ Qo, u8* __restrict__ Ko, u8* __restrict__ VTo)
{
    __shared__ __attribute__((aligned(16))) short Wt[128 * 256];  // 64 KB half
    const int tid  = threadIdx.x;
    const int lane = tid & 63;
    const int wave = tid >> 6;
    const int c16  = lane & 15;
    const int quad = lane >> 4;
    const int which = blockIdx.y;
    const int m0 = blockIdx.x * 64 + wave * 16;

    const short* W    = Wb + which * 65536;
    const float* bias = (which == 0) ? bq : (which == 1) ? bk : bv;

    bf16x8 a[8];
#pragma unroll
    for (int ke = 0; ke < 8; ++ke)
        a[ke] = ldA8(X + (m0 + c16) * 256 + ke * 32 + quad * 8);

    f32x4 acc[16];
#pragma unroll
    for (int nb = 0; nb < 16; ++nb) { f32x4 z = {0.f, 0.f, 0.f, 0.f}; acc[nb] = z; }

#pragma unroll
    for (int half = 0; half < 2; ++half) {
        if (half) __syncthreads();
        stage_rows<16>(W + half * 128 * 256, Wt, tid);
        __syncthreads();
#pragma unroll
        for (int nb8 = 0; nb8 < 8; ++nb8) {
            const int nb = half * 8 + nb8;
            const short* wr = Wt + (nb8 * 16 + c16) * 256;
#pragma unroll
            for (int ke = 0; ke < 8; ++ke) {
                bf16x8 b = *reinterpret_cast<const bf16x8*>(
                    wr + (((ke * 4 + quad) ^ (c16 & 7)) << 3));
                acc[nb] = MFMA_BF16(a[ke], b, acc[nb]);
            }
        }
    }

    if (which < 2) {
        u8* dst = (which == 0) ? Qo : Ko;
#pragma unroll
        for (int nb = 0; nb < 16; ++nb) {
            const int o = nb * 16 + c16;
            const float bb_ = bias[o];
#pragma unroll
            for (int r = 0; r < 4; ++r)
                dst[(m0 + quad * 4 + r) * 256 + o] = f2fp8(acc[nb][r] + bb_);
        }
    } else {
#pragma unroll
        for (int nb = 0; nb < 16; ++nb) {
            const int o = nb * 16 + c16;
            const float bb_ = bias[o];
            const int row = m0 + quad * 4;
            const int batch = row >> 12;
            const int n = row & 4095;
            unsigned int pk = pk4fp8(acc[nb][0] + bb_, acc[nb][1] + bb_,
                                     acc[nb][2] + bb_, acc[nb][3] + bb_);
            *reinterpret_cast<unsigned int*>(
                VTo + (size_t)batch * (256 * 4096) + o * 4096 + n) = pk;
        }
    }
}

// ---------------- split-K flash attention partial (fp8, hi-occupancy) -------
// grid 1024: combo = ((bi&7)<<1)|(bi>>9) -> 2 (batch,ks) pairs per XCD;
// qt = (bi>>3)&63. Block 256 thr = 4 waves x 16 q-rows; BK=32, 32 tiles;
// K,V fp8 double-buffered in LDS. LDS 35 KB, VGPR ~110 -> 4 blocks/CU
// (16 waves, 4/SIMD) for latency hiding.
__global__ __launch_bounds__(256, 4) void attn_part_kernel(
    const u8* __restrict__ Qb, const u8* __restrict__ Kb,
    const u8* __restrict__ VTb,
    short* __restrict__ Op, float* __restrict__ Lo)
{
    __shared__ __attribute__((aligned(16))) u8 Kt[2][32 * 256];   // 2x8 KB
    __shared__ __attribute__((aligned(16))) u8 Vt[2][256 * 32];   // 2x8 KB
    __shared__ __attribute__((aligned(16))) u8 Pb[4][16 * 40];    // 2.5 KB

    const int tid  = threadIdx.x;
    const int lane = tid & 63;
    const int wave = tid >> 6;
    const int c16  = lane & 15;
    const int quad = lane >> 4;
    const int iq   = quad & 1;
    const int qh   = quad >> 1;
    const int bi = blockIdx.x;
    const int combo = ((bi & 7) << 1) | (bi >> 9);
    const int batch = combo >> 2;
    const int ks    = combo & 3;
    const int qt    = (bi >> 3) & 63;
    const size_t bb = (size_t)batch * (4096 * 256);
    const int rw = qt * 64 + wave * 16;           // wave's 16 q rows
    const int kbase = ks * 1024;

    // Q B-fragments (for S^T = K Q^T): Q[qrow=c16][e], 8 x 8 B = 16 VGPRs
    long qf[8];
#pragma unroll
    for (int ke = 0; ke < 8; ++ke)
        qf[ke] = *reinterpret_cast<const long*>(
            Qb + bb + (rw + c16) * 256 + ke * 32 + quad * 8);

    f32x4 oa[16];
#pragma unroll
    for (int nb = 0; nb < 16; ++nb) { f32x4 z = {0.f, 0.f, 0.f, 0.f}; oa[nb] = z; }
    float lsum = 0.f;

    constexpr float K1 = 1.4426950408889634f / 64.0f;  // log2(e)/sqrt(4096)
    unsigned int* pw32 = reinterpret_cast<unsigned int*>(&Pb[wave][0]);

    // lane-constant LDS offsets
    int kx[8];
#pragma unroll
    for (int ke = 0; ke < 8; ++ke)
        kx[ke] = ((ke * 2 + qh) ^ c16) << 4;
    const int kroff = c16 * 256 + iq * 8;
    const int voff  = c16 * 32 + ((qh ^ ((c16 >> 2) & 1)) << 4) + iq * 8;

    const u8* Kg = Kb + bb + kbase * 256;
    const u8* Vg = VTb + bb + kbase;

    stage_k8(Kg, &Kt[0][0], tid);
    stage_v8(Vg, &Vt[0][0], tid);

    for (int kt = 0; kt < 32; ++kt) {
        __syncthreads();   // tile kt staged; slot (kt+1)&1 free
        if (kt + 1 < 32) {
            stage_k8(Kg + (kt + 1) * 32 * 256, &Kt[(kt + 1) & 1][0], tid);
            stage_v8(Vg + (kt + 1) * 32, &Vt[(kt + 1) & 1][0], tid);
        }
        const u8* K = &Kt[kt & 1][0];
        const u8* V = &Vt[kt & 1][0];

        // ---- S^T = K Q^T : rows = 32 keys (2 nb), cols = 16 q-rows ----
        f32x4 s[2];
        { f32x4 z = {0.f, 0.f, 0.f, 0.f}; s[0] = z; s[1] = z; }
#pragma unroll
        for (int nb = 0; nb < 2; ++nb) {
#pragma unroll
            for (int ke = 0; ke < 8; ++ke) {
                long kf = *reinterpret_cast<const long*>(K + kroff + kx[ke] + nb * 4096);
                s[nb] = MFMA_FP8(kf, qf[ke], s[nb]);
            }
        }

        // ---- p = exp2(z*K1): lane holds 4 consecutive keys of qrow c16 ----
#pragma unroll
        for (int nb = 0; nb < 2; ++nb) {
            const float p0 = exp2f(s[nb][0] * K1);
            const float p1 = exp2f(s[nb][1] * K1);
            const float p2 = exp2f(s[nb][2] * K1);
            const float p3 = exp2f(s[nb][3] * K1);
            lsum += (p0 + p1) + (p2 + p3);
            pw32[c16 * 10 + nb * 4 + quad] = pk4fp8(p0, p1, p2, p3);
        }
        // TBAA-safe readback through the same scalar type (u32), bit_cast to i64
        u32x2 aw;
        aw.x = pw32[c16 * 10 + quad * 2];
        aw.y = pw32[c16 * 10 + quad * 2 + 1];
        long ap = __builtin_bit_cast(long, aw);

        // ---- O += P V : 16 e-blocks, K=32 keys each ----
#pragma unroll
        for (int nb = 0; nb < 16; ++nb) {
            long v = *reinterpret_cast<const long*>(V + voff + nb * 512);
            oa[nb] = MFMA_FP8(ap, v, oa[nb]);
        }
    }

    // ---- l: reduce across quads (keys live on lane bits 4,5) ----
    {
        float rs = lsum;
        rs += __shfl_xor(rs, 16, 64);
        rs += __shfl_xor(rs, 32, 64);
        const size_t base = (size_t)ks * 16384 + batch * 4096 + rw;
#pragma unroll
        for (int nb = 0; nb < 16; ++nb)
#pragma unroll
            for (int r = 0; r < 4; ++r)
                Op[(base + quad * 4 + r) * 256 + nb * 16 + c16] = f2bf(oa[nb][r]);
        if (lane < 16) Lo[base + c16] = rs;
    }
}

// ---------------- merge splits + residual + LayerNorm ----------------
template <typename TRES, typename TOUT>
__global__ __launch_bounds__(256) void merge_ln_kernel(
    const short* __restrict__ Op, const float* __restrict__ Lo,
    const TRES* __restrict__ res, const float* __restrict__ gamma,
    const float* __restrict__ beta, TOUT* __restrict__ out)
{
    const int lane = threadIdx.x & 63;
    const int wave = threadIdx.x >> 6;
    const int row = blockIdx.x * 4 + wave;          // batch*4096 + local row
    const float li = 1.0f / (Lo[row] + Lo[16384 + row] +
                             Lo[32768 + row] + Lo[49152 + row]);
    const int e = lane * 4;
    float o[4] = {0.f, 0.f, 0.f, 0.f};
#pragma unroll
    for (int s = 0; s < 4; ++s) {
        ushort4 u = *reinterpret_cast<const ushort4*>(
            Op + ((size_t)s * 16384 + row) * 256 + e);
        o[0] += bf2f((short)u.x);
        o[1] += bf2f((short)u.y);
        o[2] += bf2f((short)u.z);
        o[3] += bf2f((short)u.w);
    }
    float y[4];
#pragma unroll
    for (int i = 0; i < 4; ++i)
        y[i] = o[i] * li + ld1(res + (size_t)row * 256 + e + i);

    float sum = y[0] + y[1] + y[2] + y[3];
    float sq  = y[0]*y[0] + y[1]*y[1] + y[2]*y[2] + y[3]*y[3];
#pragma unroll
    for (int d = 1; d < 64; d <<= 1) {
        sum += __shfl_xor(sum, d, 64);
        sq  += __shfl_xor(sq,  d, 64);
    }
    const float mean = sum * (1.0f / 256.0f);
    const float var  = sq * (1.0f / 256.0f) - mean * mean;
    const float rstd = rsqrtf(var + 1e-5f);
#pragma unroll
    for (int i = 0; i < 4; ++i)
        st1(out + (size_t)row * 256 + e + i,
            (y[i] - mean) * rstd * gamma[e + i] + beta[e + i]);
}

extern "C" void kernel_launch(void* const* d_in, const int* in_sizes, int n_in,
                              void* d_out, int out_size, void* d_ws, size_t ws_size,
                              hipStream_t stream) {
    const float* x   = (const float*)d_in[0];
    const float* Wq1 = (const float*)d_in[1];
    const float* bq1 = (const float*)d_in[2];
    const float* Wk1 = (const float*)d_in[3];
    const float* bk1 = (const float*)d_in[4];
    const float* Wv1 = (const float*)d_in[5];
    const float* bv1 = (const float*)d_in[6];
    const float* Wq2 = (const float*)d_in[7];
    const float* bq2 = (const float*)d_in[8];
    const float* Wk2 = (const float*)d_in[9];
    const float* bk2 = (const float*)d_in[10];
    const float* Wv2 = (const float*)d_in[11];
    const float* bv2 = (const float*)d_in[12];
    const float* g1  = (const float*)d_in[13];
    const float* be1 = (const float*)d_in[14];
    const float* g2  = (const float*)d_in[15];
    const float* be2 = (const float*)d_in[16];

    const size_t NE = (size_t)16384 * 256;   // 4,194,304
    short* O1  = (short*)d_ws;               // 8 MB (layer-1 output, bf16)
    short* Wb  = O1 + NE;                    // 6 x 65536 bf16
    u8*    Qb  = (u8*)(Wb + 6 * 65536);      // fp8, 4 MB
    u8*    Kb  = Qb + NE;                    // fp8, 4 MB
    u8*    VTb = Kb + NE;                    // fp8, 4 MB
    short* Op  = (short*)(VTb + NE);         // 4 x 16384 x 256 bf16 = 32 MB
    float* Lo  = (float*)(Op + 4 * NE);      // 4 x 16384 fp32
    float* outp = (float*)d_out;

    dim3 pgrid(256, 3), pblk(256);

    cvt_w_kernel<<<192, 256, 0, stream>>>(Wq1, Wk1, Wv1, Wq2, Wk2, Wv2, Wb);

    qkv_proj_kernel<float><<<pgrid, pblk, 0, stream>>>(
        x, Wb, bq1, bk1, bv1, Qb, Kb, VTb);
    attn_part_kernel<<<1024, 256, 0, stream>>>(Qb, Kb, VTb, Op, Lo);
    merge_ln_kernel<float, short><<<4096, 256, 0, stream>>>(Op, Lo, x, g1, be1, O1);

    qkv_proj_kernel<short><<<pgrid, pblk, 0, stream>>>(
        O1, Wb + 3 * 65536, bq2, bk2, bv2, Qb, Kb, VTb);
    attn_part_kernel<<<1024, 256, 0, stream>>>(Qb, Kb, VTb, Op, Lo);
    merge_ln_kernel<short, float><<<4096, 256, 0, stream>>>(Op, Lo, O1, g2, be2, outp);
}